// Round 1
// baseline (1527.400 us; speedup 1.0000x reference)
//
#include <hip/hip_runtime.h>
#include <hip/hip_bf16.h>

#define B_ 32
#define T_ 512
#define L_ 2048
#define H_ 512
#define NRR (B_*T_)      /* 16384 rows */
#define KC_ 1536         /* 3*H */
#define NB_ 256
#define EPS_ 1e-5f

typedef __bf16 bf16;
typedef __bf16 bf16x8 __attribute__((ext_vector_type(8)));
typedef float f32x4 __attribute__((ext_vector_type(4)));

static const size_t WC_BYTES = (size_t)6 * H_ * KC_ * 2;   // 9,437,184
static const size_t Y_BYTES  = (size_t)NRR * H_ * 4;       // 33,554,432
static const size_t N_BYTES  = (size_t)NRR * H_ * 2;       // 16,777,216

// ---------------- weight repack: w[i][o][c][k] -> Wc[m][o][k*H + c] (bf16) ----
__global__ void k_prep_wc(const float* __restrict__ wd, const float* __restrict__ wp,
                          const float* __restrict__ we, bf16* __restrict__ wc) {
    int e = blockIdx.x * 256 + threadIdx.x;
    if (e >= 6 * H_ * KC_) return;
    int m   = e / (H_ * KC_);
    int rem = e % (H_ * KC_);
    int o  = rem / KC_;
    int r2 = rem % KC_;
    int k  = r2 / H_;
    int c  = r2 % H_;
    int p = m >> 1, i = m & 1;
    const float* w = (p == 0) ? wd : (p == 1 ? wp : we);
    float v = w[((size_t)i * H_ * H_ + (size_t)o * H_ + c) * 3 + k];
    wc[e] = (bf16)v;
}

// ---------------- bucketize (searchsorted left over 255 bins) ----------------
__global__ void k_buckets(const float* __restrict__ pt, const float* __restrict__ et,
                          const float* __restrict__ pbins, const float* __restrict__ ebins,
                          int* __restrict__ pidx, int* __restrict__ eidx) {
    int r = blockIdx.x * 256 + threadIdx.x;
    if (r >= NRR) return;
    {
        float v = pt[r];
        int lo = 0, hi = NB_ - 1;          // 255 bins
        while (lo < hi) { int mid = (lo + hi) >> 1; if (pbins[mid] < v) lo = mid + 1; else hi = mid; }
        pidx[r] = lo;
    }
    {
        float v = et[r];
        int lo = 0, hi = NB_ - 1;
        while (lo < hi) { int mid = (lo + hi) >> 1; if (ebins[mid] < v) lo = mid + 1; else hi = mid; }
        eidx[r] = lo;
    }
}

// ---------------- per-batch inclusive scan of durations ----------------------
__global__ void k_scan(const int* __restrict__ dur, int* __restrict__ csum,
                       float* __restrict__ mel_out) {
    int b = blockIdx.x, t = threadIdx.x;
    __shared__ int s[T_];
    s[t] = dur[b * T_ + t];
    __syncthreads();
    for (int off = 1; off < T_; off <<= 1) {
        int v = (t >= off) ? s[t - off] : 0;
        __syncthreads();
        s[t] += v;
        __syncthreads();
    }
    csum[b * T_ + t] = s[t];
    if (t == T_ - 1) mel_out[b] = (float)((s[t] < L_) ? s[t] : L_);
}

// ---------------- length regulate + (x + p_emb + e_emb) gather ---------------
__global__ void k_gather(const float* __restrict__ x, const float* __restrict__ pemb,
                         const float* __restrict__ eemb, const int* __restrict__ pidx,
                         const int* __restrict__ eidx, const int* __restrict__ csum,
                         float* __restrict__ out) {
    int bi = blockIdx.x;
    int b  = bi >> 9;
    int l0 = (bi & 511) << 2;
    __shared__ int cs[T_];
    cs[threadIdx.x]       = csum[b * T_ + threadIdx.x];
    cs[threadIdx.x + 256] = csum[b * T_ + threadIdx.x + 256];
    __syncthreads();
    int wid = threadIdx.x >> 6, lane = threadIdx.x & 63;
    int l = l0 + wid;
    int mel = cs[T_ - 1]; if (mel > L_) mel = L_;
    float* op = out + ((size_t)(b * L_ + l)) * H_ + lane * 8;
    if (l >= mel) {
        f32x4 z = {0.f, 0.f, 0.f, 0.f};
        ((f32x4*)op)[0] = z;
        ((f32x4*)op)[1] = z;
        return;
    }
    int lo = 0, hi = T_;
    while (lo < hi) { int mid = (lo + hi) >> 1; if (cs[mid] <= l) lo = mid + 1; else hi = mid; }
    int idx = (lo < T_ - 1) ? lo : (T_ - 1);
    int rr = b * T_ + idx;
    int pi = pidx[rr], ei = eidx[rr];
    const f32x4* xp = (const f32x4*)(x    + (size_t)rr * H_ + lane * 8);
    const f32x4* pp = (const f32x4*)(pemb + (size_t)pi * H_ + lane * 8);
    const f32x4* ep = (const f32x4*)(eemb + (size_t)ei * H_ + lane * 8);
    ((f32x4*)op)[0] = xp[0] + pp[0] + ep[0];
    ((f32x4*)op)[1] = xp[1] + pp[1] + ep[1];
}

// ---------------- conv-as-GEMM: Y[r][o] = relu(sum_kc A[r][kc]*W[o][kc] + bias[o]) ----
// A[r][k*H+c] = Ain[b, t+k-1, c] (zero-padded in t), r = b*T+t
template<bool AF32>
__global__ void k_conv_gemm(const float* __restrict__ Af, const bf16* __restrict__ Ab,
                            const bf16* __restrict__ W, const float* __restrict__ bias,
                            float* __restrict__ Y) {
    int tid  = threadIdx.x;
    int w    = tid >> 6, lane = tid & 63;
    int rl   = lane & 15;         // row-in-16 (A) / col-in-16 (B)
    int kq   = lane >> 4;         // k-quad: elements 8*kq..8*kq+7
    int rowBase = blockIdx.x * 64 + w * 16;
    int colBase = blockIdx.y * 64;
    int r  = rowBase + rl;
    int bb = r >> 9;
    int t  = r & (T_ - 1);

    f32x4 acc0 = {0,0,0,0}, acc1 = {0,0,0,0}, acc2 = {0,0,0,0}, acc3 = {0,0,0,0};
    const bf16* w0 = W + (size_t)(colBase + rl) * KC_ + 8 * kq;
    const bf16* w1 = w0 + (size_t)16 * KC_;
    const bf16* w2 = w0 + (size_t)32 * KC_;
    const bf16* w3 = w0 + (size_t)48 * KC_;

    for (int j = 0; j < 48; ++j) {
        int kc = j * 32;
        int k  = kc >> 9;
        int c0 = kc & (H_ - 1);
        int tt = t + k - 1;
        bf16x8 a;
        if (tt >= 0 && tt < T_) {
            size_t off = ((size_t)(bb * T_ + tt)) * H_ + c0 + 8 * kq;
            if constexpr (AF32) {
                const f32x4* p = (const f32x4*)(Af + off);
                f32x4 u = p[0], v = p[1];
                a[0] = (bf16)u[0]; a[1] = (bf16)u[1]; a[2] = (bf16)u[2]; a[3] = (bf16)u[3];
                a[4] = (bf16)v[0]; a[5] = (bf16)v[1]; a[6] = (bf16)v[2]; a[7] = (bf16)v[3];
            } else {
                a = *(const bf16x8*)(Ab + off);
            }
        } else {
#pragma unroll
            for (int q = 0; q < 8; ++q) a[q] = (bf16)0.0f;
        }
        bf16x8 b0 = *(const bf16x8*)(w0 + kc);
        bf16x8 b1 = *(const bf16x8*)(w1 + kc);
        bf16x8 b2 = *(const bf16x8*)(w2 + kc);
        bf16x8 b3 = *(const bf16x8*)(w3 + kc);
        acc0 = __builtin_amdgcn_mfma_f32_16x16x32_bf16(a, b0, acc0, 0, 0, 0);
        acc1 = __builtin_amdgcn_mfma_f32_16x16x32_bf16(a, b1, acc1, 0, 0, 0);
        acc2 = __builtin_amdgcn_mfma_f32_16x16x32_bf16(a, b2, acc2, 0, 0, 0);
        acc3 = __builtin_amdgcn_mfma_f32_16x16x32_bf16(a, b3, acc3, 0, 0, 0);
    }
    // D layout: col = lane&15, row = 4*(lane>>4) + reg   [m89-verified]
    int rr0 = rowBase + 4 * kq;
    {
        int o = colBase + 0 + rl; float bi = bias[o];
        Y[(size_t)(rr0 + 0) * H_ + o] = fmaxf(acc0[0] + bi, 0.f);
        Y[(size_t)(rr0 + 1) * H_ + o] = fmaxf(acc0[1] + bi, 0.f);
        Y[(size_t)(rr0 + 2) * H_ + o] = fmaxf(acc0[2] + bi, 0.f);
        Y[(size_t)(rr0 + 3) * H_ + o] = fmaxf(acc0[3] + bi, 0.f);
    }
    {
        int o = colBase + 16 + rl; float bi = bias[o];
        Y[(size_t)(rr0 + 0) * H_ + o] = fmaxf(acc1[0] + bi, 0.f);
        Y[(size_t)(rr0 + 1) * H_ + o] = fmaxf(acc1[1] + bi, 0.f);
        Y[(size_t)(rr0 + 2) * H_ + o] = fmaxf(acc1[2] + bi, 0.f);
        Y[(size_t)(rr0 + 3) * H_ + o] = fmaxf(acc1[3] + bi, 0.f);
    }
    {
        int o = colBase + 32 + rl; float bi = bias[o];
        Y[(size_t)(rr0 + 0) * H_ + o] = fmaxf(acc2[0] + bi, 0.f);
        Y[(size_t)(rr0 + 1) * H_ + o] = fmaxf(acc2[1] + bi, 0.f);
        Y[(size_t)(rr0 + 2) * H_ + o] = fmaxf(acc2[2] + bi, 0.f);
        Y[(size_t)(rr0 + 3) * H_ + o] = fmaxf(acc2[3] + bi, 0.f);
    }
    {
        int o = colBase + 48 + rl; float bi = bias[o];
        Y[(size_t)(rr0 + 0) * H_ + o] = fmaxf(acc3[0] + bi, 0.f);
        Y[(size_t)(rr0 + 1) * H_ + o] = fmaxf(acc3[1] + bi, 0.f);
        Y[(size_t)(rr0 + 2) * H_ + o] = fmaxf(acc3[2] + bi, 0.f);
        Y[(size_t)(rr0 + 3) * H_ + o] = fmaxf(acc3[3] + bi, 0.f);
    }
}

// ---------------- LayerNorm over H (input is already relu'd), write bf16 -----
__global__ void k_ln(const float* __restrict__ Yin, const float* __restrict__ g,
                     const float* __restrict__ bta, bf16* __restrict__ nout) {
    int wid = threadIdx.x >> 6, lane = threadIdx.x & 63;
    int r = blockIdx.x * 4 + wid;
    const f32x4* row = (const f32x4*)(Yin + (size_t)r * H_);
    f32x4 u = row[lane * 2], v = row[lane * 2 + 1];
    float s1 = u[0] + u[1] + u[2] + u[3] + v[0] + v[1] + v[2] + v[3];
    float s2 = u[0]*u[0] + u[1]*u[1] + u[2]*u[2] + u[3]*u[3]
             + v[0]*v[0] + v[1]*v[1] + v[2]*v[2] + v[3]*v[3];
    for (int m = 1; m < 64; m <<= 1) { s1 += __shfl_xor(s1, m); s2 += __shfl_xor(s2, m); }
    float mean = s1 * (1.f / H_);
    float var  = s2 * (1.f / H_) - mean * mean;
    float rs   = rsqrtf(var + EPS_);
    const f32x4* gp = (const f32x4*)g;
    const f32x4* bp = (const f32x4*)bta;
    f32x4 g0 = gp[lane * 2], g1 = gp[lane * 2 + 1];
    f32x4 b0 = bp[lane * 2], b1 = bp[lane * 2 + 1];
    bf16x8 o;
    o[0] = (bf16)((u[0] - mean) * rs * g0[0] + b0[0]);
    o[1] = (bf16)((u[1] - mean) * rs * g0[1] + b0[1]);
    o[2] = (bf16)((u[2] - mean) * rs * g0[2] + b0[2]);
    o[3] = (bf16)((u[3] - mean) * rs * g0[3] + b0[3]);
    o[4] = (bf16)((v[0] - mean) * rs * g1[0] + b1[0]);
    o[5] = (bf16)((v[1] - mean) * rs * g1[1] + b1[1]);
    o[6] = (bf16)((v[2] - mean) * rs * g1[2] + b1[2]);
    o[7] = (bf16)((v[3] - mean) * rs * g1[3] + b1[3]);
    *(bf16x8*)(nout + (size_t)r * H_ + lane * 8) = o;
}

// ---------------- final linear H->1, mask ------------------------------------
__global__ void k_linear(const bf16* __restrict__ nin, const float* __restrict__ lw,
                         const float* __restrict__ lb, const unsigned char* __restrict__ mask,
                         float* __restrict__ outp) {
    int wid = threadIdx.x >> 6, lane = threadIdx.x & 63;
    int r = blockIdx.x * 4 + wid;
    bf16x8 a = *(const bf16x8*)(nin + (size_t)r * H_ + lane * 8);
    const f32x4* wp = (const f32x4*)lw;
    f32x4 w0 = wp[lane * 2], w1 = wp[lane * 2 + 1];
    float s = (float)a[0]*w0[0] + (float)a[1]*w0[1] + (float)a[2]*w0[2] + (float)a[3]*w0[3]
            + (float)a[4]*w1[0] + (float)a[5]*w1[1] + (float)a[6]*w1[2] + (float)a[7]*w1[3];
    for (int m = 1; m < 64; m <<= 1) s += __shfl_xor(s, m);
    if (lane == 0) outp[r] = mask[r] ? 0.f : (s + lb[0]);
}

extern "C" void kernel_launch(void* const* d_in, const int* in_sizes, int n_in,
                              void* d_out, int out_size, void* d_ws, size_t ws_size,
                              hipStream_t stream) {
    const float* x  = (const float*)d_in[0];
    const unsigned char* mask = (const unsigned char*)d_in[1];
    const int*   dur = (const int*)d_in[2];
    const float* pt  = (const float*)d_in[3];
    const float* et  = (const float*)d_in[4];
    const float* cw[3]    = {(const float*)d_in[6],  (const float*)d_in[12], (const float*)d_in[18]};
    const float* cb[3]    = {(const float*)d_in[7],  (const float*)d_in[13], (const float*)d_in[19]};
    const float* lg[3]    = {(const float*)d_in[8],  (const float*)d_in[14], (const float*)d_in[20]};
    const float* lbn[3]   = {(const float*)d_in[9],  (const float*)d_in[15], (const float*)d_in[21]};
    const float* lw[3]    = {(const float*)d_in[10], (const float*)d_in[16], (const float*)d_in[22]};
    const float* lbias[3] = {(const float*)d_in[11], (const float*)d_in[17], (const float*)d_in[23]};
    const float* pbins = (const float*)d_in[24];
    const float* ebins = (const float*)d_in[25];
    const float* pemb  = (const float*)d_in[26];
    const float* eemb  = (const float*)d_in[27];

    float* out0 = (float*)d_out;
    const size_t OUT0 = (size_t)B_ * L_ * H_;
    float* pitch_out  = out0 + OUT0;
    float* energy_out = pitch_out + NRR;
    float* logd_out   = energy_out + NRR;
    float* mel_out    = logd_out + NRR;

    char* ws = (char*)d_ws;
    bf16*  wc   = (bf16*)ws;
    float* y    = (float*)(ws + WC_BYTES);
    bf16*  nbuf = (bf16*)(ws + WC_BYTES + Y_BYTES);
    int*   csum = (int*)(ws + WC_BYTES + Y_BYTES + N_BYTES);
    int*   pidx = csum + NRR;
    int*   eidx = pidx + NRR;

    k_prep_wc<<<(6 * H_ * KC_ + 255) / 256, 256, 0, stream>>>(cw[0], cw[1], cw[2], wc);
    k_buckets<<<(NRR + 255) / 256, 256, 0, stream>>>(pt, et, pbins, ebins, pidx, eidx);
    k_scan<<<B_, T_, 0, stream>>>(dur, csum, mel_out);
    k_gather<<<B_ * L_ / 4, 256, 0, stream>>>(x, pemb, eemb, pidx, eidx, csum, out0);

    float* preds[3] = {logd_out, pitch_out, energy_out};
    dim3 grid(NRR / 64, H_ / 64);
    for (int p = 0; p < 3; ++p) {
        const bf16* wc0 = wc + (size_t)(2 * p + 0) * H_ * KC_;
        const bf16* wc1 = wc + (size_t)(2 * p + 1) * H_ * KC_;
        k_conv_gemm<true ><<<grid, 256, 0, stream>>>(x, nullptr, wc0, cb[p],      y);
        k_ln<<<NRR / 4, 256, 0, stream>>>(y, lg[p],      lbn[p],      nbuf);
        k_conv_gemm<false><<<grid, 256, 0, stream>>>(nullptr, nbuf, wc1, cb[p] + H_, y);
        k_ln<<<NRR / 4, 256, 0, stream>>>(y, lg[p] + H_, lbn[p] + H_, nbuf);
        k_linear<<<NRR / 4, 256, 0, stream>>>(nbuf, lw[p], lbias[p], mask, preds[p]);
    }
}

// Round 2
// 349.197 us; speedup vs baseline: 4.3740x; 4.3740x over previous
//
#include <hip/hip_runtime.h>
#include <hip/hip_bf16.h>

#define B_ 32
#define T_ 512
#define TP_ 514          /* padded rows per batch */
#define L_ 2048
#define H_ 512
#define NRR (B_*T_)      /* 16384 rows */
#define KC_ 1536         /* 3*H */
#define NB_ 256
#define EPS_ 1e-5f

typedef __bf16 bf16;
typedef __bf16 bf16x8 __attribute__((ext_vector_type(8)));
typedef float f32x4 __attribute__((ext_vector_type(4)));

static const size_t WC_BYTES  = (size_t)6 * H_ * KC_ * 2;       // 9,437,184
static const size_t XP_BYTES  = (size_t)B_ * TP_ * H_ * 2;      // 16,842,752
static const size_t Y_BYTES   = (size_t)NRR * H_ * 2;           // 16,777,216

__device__ __forceinline__ void gload16(const void* g, void* l) {
    __builtin_amdgcn_global_load_lds(
        (const __attribute__((address_space(1))) unsigned int*)g,
        (__attribute__((address_space(3))) unsigned int*)l, 16, 0, 0);
}

// ---------------- weight repack: w[i][o][c][k] -> Wc[m][o][k*H + c] (bf16) ----
__global__ void k_prep_wc(const float* __restrict__ wd, const float* __restrict__ wp,
                          const float* __restrict__ we, bf16* __restrict__ wc) {
    int e = blockIdx.x * 256 + threadIdx.x;
    if (e >= 6 * H_ * KC_) return;
    int m   = e / (H_ * KC_);
    int rem = e % (H_ * KC_);
    int o  = rem / KC_;
    int r2 = rem % KC_;
    int k  = r2 / H_;
    int c  = r2 % H_;
    int p = m >> 1, i = m & 1;
    const float* w = (p == 0) ? wd : (p == 1 ? wp : we);
    float v = w[((size_t)i * H_ * H_ + (size_t)o * H_ + c) * 3 + k];
    wc[e] = (bf16)v;
}

// ---------------- padded bf16 input: xp0[b][tp][c], tp=0 and 513 are zero ----
__global__ void k_pad(const float* __restrict__ x, bf16* __restrict__ xp0,
                      bf16* __restrict__ xp1) {
    int wid = threadIdx.x >> 6, lane = threadIdx.x & 63;
    int row = blockIdx.x * 4 + wid;               // 0 .. 32*514-1
    int b = row / TP_, tp = row % TP_;
    bf16* d0 = xp0 + (size_t)row * H_ + lane * 8;
    if (tp == 0 || tp == TP_ - 1) {
        bf16x8 z;
#pragma unroll
        for (int i = 0; i < 8; ++i) z[i] = (bf16)0.0f;
        *(bf16x8*)d0 = z;
        *(bf16x8*)(xp1 + (size_t)row * H_ + lane * 8) = z;
    } else {
        const f32x4* p = (const f32x4*)(x + ((size_t)(b * T_ + tp - 1)) * H_ + lane * 8);
        f32x4 u = p[0], v = p[1];
        bf16x8 o;
        o[0] = (bf16)u[0]; o[1] = (bf16)u[1]; o[2] = (bf16)u[2]; o[3] = (bf16)u[3];
        o[4] = (bf16)v[0]; o[5] = (bf16)v[1]; o[6] = (bf16)v[2]; o[7] = (bf16)v[3];
        *(bf16x8*)d0 = o;
    }
}

// ---------------- bucketize (searchsorted left over 255 bins) ----------------
__global__ void k_buckets(const float* __restrict__ pt, const float* __restrict__ et,
                          const float* __restrict__ pbins, const float* __restrict__ ebins,
                          int* __restrict__ pidx, int* __restrict__ eidx) {
    int r = blockIdx.x * 256 + threadIdx.x;
    if (r >= NRR) return;
    {
        float v = pt[r];
        int lo = 0, hi = NB_ - 1;
        while (lo < hi) { int mid = (lo + hi) >> 1; if (pbins[mid] < v) lo = mid + 1; else hi = mid; }
        pidx[r] = lo;
    }
    {
        float v = et[r];
        int lo = 0, hi = NB_ - 1;
        while (lo < hi) { int mid = (lo + hi) >> 1; if (ebins[mid] < v) lo = mid + 1; else hi = mid; }
        eidx[r] = lo;
    }
}

// ---------------- per-batch inclusive scan of durations ----------------------
__global__ void k_scan(const int* __restrict__ dur, int* __restrict__ csum,
                       float* __restrict__ mel_out) {
    int b = blockIdx.x, t = threadIdx.x;
    __shared__ int s[T_];
    s[t] = dur[b * T_ + t];
    __syncthreads();
    for (int off = 1; off < T_; off <<= 1) {
        int v = (t >= off) ? s[t - off] : 0;
        __syncthreads();
        s[t] += v;
        __syncthreads();
    }
    csum[b * T_ + t] = s[t];
    if (t == T_ - 1) mel_out[b] = (float)((s[t] < L_) ? s[t] : L_);
}

// ---------------- length regulate + (x + p_emb + e_emb) gather ---------------
__global__ void k_gather(const float* __restrict__ x, const float* __restrict__ pemb,
                         const float* __restrict__ eemb, const int* __restrict__ pidx,
                         const int* __restrict__ eidx, const int* __restrict__ csum,
                         float* __restrict__ out) {
    int bi = blockIdx.x;
    int b  = bi >> 9;
    int l0 = (bi & 511) << 2;
    __shared__ int cs[T_];
    cs[threadIdx.x]       = csum[b * T_ + threadIdx.x];
    cs[threadIdx.x + 256] = csum[b * T_ + threadIdx.x + 256];
    __syncthreads();
    int wid = threadIdx.x >> 6, lane = threadIdx.x & 63;
    int l = l0 + wid;
    int mel = cs[T_ - 1]; if (mel > L_) mel = L_;
    float* op = out + ((size_t)(b * L_ + l)) * H_ + lane * 8;
    if (l >= mel) {
        f32x4 z = {0.f, 0.f, 0.f, 0.f};
        ((f32x4*)op)[0] = z;
        ((f32x4*)op)[1] = z;
        return;
    }
    int lo = 0, hi = T_;
    while (lo < hi) { int mid = (lo + hi) >> 1; if (cs[mid] <= l) lo = mid + 1; else hi = mid; }
    int idx = (lo < T_ - 1) ? lo : (T_ - 1);
    int rr = b * T_ + idx;
    int pi = pidx[rr], ei = eidx[rr];
    const f32x4* xp = (const f32x4*)(x    + (size_t)rr * H_ + lane * 8);
    const f32x4* pp = (const f32x4*)(pemb + (size_t)pi * H_ + lane * 8);
    const f32x4* ep = (const f32x4*)(eemb + (size_t)ei * H_ + lane * 8);
    ((f32x4*)op)[0] = xp[0] + pp[0] + ep[0];
    ((f32x4*)op)[1] = xp[1] + pp[1] + ep[1];
}

// ---------------- tiled conv-as-GEMM (m97 structure) -------------------------
// C[r][o] = relu( sum_{kc} Xp[b][t + (kc>>9)][kc&511] * W[o][kc] + bias[o] )
// Xp is padded: row tp = t+1 holds x[b][t]; tp=0/513 are zeros.
// Tile 128x128, BK=64, 4 waves (2x2), global_load_lds(16B), Y out bf16.
__global__ void k_gemm(const bf16* __restrict__ Xp, const bf16* __restrict__ W,
                       const float* __restrict__ bias, bf16* __restrict__ Y) {
    __shared__ bf16 lA[128 * 64];
    __shared__ bf16 lB[128 * 64];
    int tid = threadIdx.x;
    int wid = tid >> 6, lane = tid & 63;
    int wr = wid >> 1, wc = wid & 1;
    int rowBase = blockIdx.y * 128;
    int colBase = blockIdx.x * 128;
    int b  = rowBase >> 9;
    int t0 = rowBase & (T_ - 1);

    f32x4 acc[4][4];
#pragma unroll
    for (int m = 0; m < 4; ++m)
#pragma unroll
        for (int n = 0; n < 4; ++n) acc[m][n] = (f32x4){0.f, 0.f, 0.f, 0.f};

    int lr = lane & 15, kq = lane >> 4;
    int rsub = lane >> 3, csub = (lane & 7) << 3;    // staging: row-in-8, col elem

    for (int step = 0; step < 24; ++step) {
        int k  = step >> 3;
        int c0 = (step & 7) << 6;
        // A: rows rowBase..+127 -> padded rows b*514 + t0 + k + r   (t0+r+k-1 +1)
        const bf16* srcA = Xp + ((size_t)(b * TP_ + t0 + k)) * H_ + c0;
        const bf16* srcB = W + (size_t)colBase * KC_ + step * 64;
#pragma unroll
        for (int q = 0; q < 4; ++q) {
            int r0 = (wid * 4 + q) * 8;
            gload16(srcA + (size_t)(r0 + rsub) * H_  + csub, &lA[r0 * 64]);
            gload16(srcB + (size_t)(r0 + rsub) * KC_ + csub, &lB[r0 * 64]);
        }
        __syncthreads();
#pragma unroll
        for (int kk = 0; kk < 64; kk += 32) {
            bf16x8 af[4], bfr[4];
#pragma unroll
            for (int m = 0; m < 4; ++m)
                af[m] = *(const bf16x8*)&lA[(wr * 64 + m * 16 + lr) * 64 + kk + kq * 8];
#pragma unroll
            for (int n = 0; n < 4; ++n)
                bfr[n] = *(const bf16x8*)&lB[(wc * 64 + n * 16 + lr) * 64 + kk + kq * 8];
#pragma unroll
            for (int m = 0; m < 4; ++m)
#pragma unroll
                for (int n = 0; n < 4; ++n)
                    acc[m][n] = __builtin_amdgcn_mfma_f32_16x16x32_bf16(af[m], bfr[n], acc[m][n], 0, 0, 0);
        }
        __syncthreads();
    }

    // D layout: col = lane&15 (o), row = 4*(lane>>4) + reg
#pragma unroll
    for (int n = 0; n < 4; ++n) {
        int o = colBase + wc * 64 + n * 16 + lr;
        float bi = bias[o];
#pragma unroll
        for (int m = 0; m < 4; ++m) {
            int row = rowBase + wr * 64 + m * 16 + 4 * kq;
#pragma unroll
            for (int r = 0; r < 4; ++r)
                Y[(size_t)(row + r) * H_ + o] = (bf16)fmaxf(acc[m][n][r] + bi, 0.f);
        }
    }
}

// ---------------- LayerNorm over H (bf16 in), write padded bf16 --------------
__global__ void k_ln_store(const bf16* __restrict__ Yin, const float* __restrict__ g,
                           const float* __restrict__ bta, bf16* __restrict__ xp1) {
    int wid = threadIdx.x >> 6, lane = threadIdx.x & 63;
    int r = blockIdx.x * 4 + wid;
    bf16x8 a = *(const bf16x8*)(Yin + (size_t)r * H_ + lane * 8);
    float f[8];
#pragma unroll
    for (int i = 0; i < 8; ++i) f[i] = (float)a[i];
    float s1 = 0.f, s2 = 0.f;
#pragma unroll
    for (int i = 0; i < 8; ++i) { s1 += f[i]; s2 += f[i] * f[i]; }
    for (int m = 1; m < 64; m <<= 1) { s1 += __shfl_xor(s1, m); s2 += __shfl_xor(s2, m); }
    float mean = s1 * (1.f / H_);
    float var  = s2 * (1.f / H_) - mean * mean;
    float rs   = rsqrtf(var + EPS_);
    const f32x4* gp = (const f32x4*)g;
    const f32x4* bp = (const f32x4*)bta;
    f32x4 g0 = gp[lane * 2], g1 = gp[lane * 2 + 1];
    f32x4 b0 = bp[lane * 2], b1 = bp[lane * 2 + 1];
    bf16x8 o;
    o[0] = (bf16)((f[0] - mean) * rs * g0[0] + b0[0]);
    o[1] = (bf16)((f[1] - mean) * rs * g0[1] + b0[1]);
    o[2] = (bf16)((f[2] - mean) * rs * g0[2] + b0[2]);
    o[3] = (bf16)((f[3] - mean) * rs * g0[3] + b0[3]);
    o[4] = (bf16)((f[4] - mean) * rs * g1[0] + b1[0]);
    o[5] = (bf16)((f[5] - mean) * rs * g1[1] + b1[1]);
    o[6] = (bf16)((f[6] - mean) * rs * g1[2] + b1[2]);
    o[7] = (bf16)((f[7] - mean) * rs * g1[3] + b1[3]);
    int bb = r >> 9, t = r & (T_ - 1);
    *(bf16x8*)(xp1 + ((size_t)(bb * TP_ + t + 1)) * H_ + lane * 8) = o;
}

// ---------------- LayerNorm + final linear H->1 + mask -----------------------
__global__ void k_ln_linear(const bf16* __restrict__ Yin, const float* __restrict__ g,
                            const float* __restrict__ bta, const float* __restrict__ lw,
                            const float* __restrict__ lb, const unsigned char* __restrict__ mask,
                            float* __restrict__ outp) {
    int wid = threadIdx.x >> 6, lane = threadIdx.x & 63;
    int r = blockIdx.x * 4 + wid;
    bf16x8 a = *(const bf16x8*)(Yin + (size_t)r * H_ + lane * 8);
    float f[8];
#pragma unroll
    for (int i = 0; i < 8; ++i) f[i] = (float)a[i];
    float s1 = 0.f, s2 = 0.f;
#pragma unroll
    for (int i = 0; i < 8; ++i) { s1 += f[i]; s2 += f[i] * f[i]; }
    for (int m = 1; m < 64; m <<= 1) { s1 += __shfl_xor(s1, m); s2 += __shfl_xor(s2, m); }
    float mean = s1 * (1.f / H_);
    float var  = s2 * (1.f / H_) - mean * mean;
    float rs   = rsqrtf(var + EPS_);
    const f32x4* gp = (const f32x4*)g;
    const f32x4* bp = (const f32x4*)bta;
    const f32x4* wp = (const f32x4*)lw;
    f32x4 g0 = gp[lane * 2], g1 = gp[lane * 2 + 1];
    f32x4 b0 = bp[lane * 2], b1 = bp[lane * 2 + 1];
    f32x4 w0 = wp[lane * 2], w1 = wp[lane * 2 + 1];
    float s = ((f[0] - mean) * rs * g0[0] + b0[0]) * w0[0]
            + ((f[1] - mean) * rs * g0[1] + b0[1]) * w0[1]
            + ((f[2] - mean) * rs * g0[2] + b0[2]) * w0[2]
            + ((f[3] - mean) * rs * g0[3] + b0[3]) * w0[3]
            + ((f[4] - mean) * rs * g1[0] + b1[0]) * w1[0]
            + ((f[5] - mean) * rs * g1[1] + b1[1]) * w1[1]
            + ((f[6] - mean) * rs * g1[2] + b1[2]) * w1[2]
            + ((f[7] - mean) * rs * g1[3] + b1[3]) * w1[3];
    for (int m = 1; m < 64; m <<= 1) s += __shfl_xor(s, m);
    if (lane == 0) outp[r] = mask[r] ? 0.f : (s + lb[0]);
}

extern "C" void kernel_launch(void* const* d_in, const int* in_sizes, int n_in,
                              void* d_out, int out_size, void* d_ws, size_t ws_size,
                              hipStream_t stream) {
    const float* x  = (const float*)d_in[0];
    const unsigned char* mask = (const unsigned char*)d_in[1];
    const int*   dur = (const int*)d_in[2];
    const float* pt  = (const float*)d_in[3];
    const float* et  = (const float*)d_in[4];
    const float* cw[3]    = {(const float*)d_in[6],  (const float*)d_in[12], (const float*)d_in[18]};
    const float* cb[3]    = {(const float*)d_in[7],  (const float*)d_in[13], (const float*)d_in[19]};
    const float* lg[3]    = {(const float*)d_in[8],  (const float*)d_in[14], (const float*)d_in[20]};
    const float* lbn[3]   = {(const float*)d_in[9],  (const float*)d_in[15], (const float*)d_in[21]};
    const float* lw[3]    = {(const float*)d_in[10], (const float*)d_in[16], (const float*)d_in[22]};
    const float* lbias[3] = {(const float*)d_in[11], (const float*)d_in[17], (const float*)d_in[23]};
    const float* pbins = (const float*)d_in[24];
    const float* ebins = (const float*)d_in[25];
    const float* pemb  = (const float*)d_in[26];
    const float* eemb  = (const float*)d_in[27];

    float* out0 = (float*)d_out;
    const size_t OUT0 = (size_t)B_ * L_ * H_;
    float* pitch_out  = out0 + OUT0;
    float* energy_out = pitch_out + NRR;
    float* logd_out   = energy_out + NRR;
    float* mel_out    = logd_out + NRR;

    char* ws = (char*)d_ws;
    bf16*  wc   = (bf16*)ws;
    bf16*  xp0  = (bf16*)(ws + WC_BYTES);
    bf16*  xp1  = (bf16*)(ws + WC_BYTES + XP_BYTES);
    bf16*  y    = (bf16*)(ws + WC_BYTES + 2 * XP_BYTES);
    int*   csum = (int*)(ws + WC_BYTES + 2 * XP_BYTES + Y_BYTES);
    int*   pidx = csum + NRR;
    int*   eidx = pidx + NRR;

    k_prep_wc<<<(6 * H_ * KC_ + 255) / 256, 256, 0, stream>>>(cw[0], cw[1], cw[2], wc);
    k_pad<<<B_ * TP_ / 4, 256, 0, stream>>>(x, xp0, xp1);
    k_buckets<<<(NRR + 255) / 256, 256, 0, stream>>>(pt, et, pbins, ebins, pidx, eidx);
    k_scan<<<B_, T_, 0, stream>>>(dur, csum, mel_out);
    k_gather<<<B_ * L_ / 4, 256, 0, stream>>>(x, pemb, eemb, pidx, eidx, csum, out0);

    float* preds[3] = {logd_out, pitch_out, energy_out};
    dim3 grid(H_ / 128, NRR / 128);   // x = col-block (4), y = row-block (128)
    for (int p = 0; p < 3; ++p) {
        const bf16* wc0 = wc + (size_t)(2 * p + 0) * H_ * KC_;
        const bf16* wc1 = wc + (size_t)(2 * p + 1) * H_ * KC_;
        k_gemm<<<grid, 256, 0, stream>>>(xp0, wc0, cb[p], y);
        k_ln_store<<<NRR / 4, 256, 0, stream>>>(y, lg[p], lbn[p], xp1);
        k_gemm<<<grid, 256, 0, stream>>>(xp1, wc1, cb[p] + H_, y);
        k_ln_linear<<<NRR / 4, 256, 0, stream>>>(y, lg[p] + H_, lbn[p] + H_,
                                                 lw[p], lbias[p], mask, preds[p]);
    }
}

// Round 3
// 302.154 us; speedup vs baseline: 5.0550x; 1.1557x over previous
//
#include <hip/hip_runtime.h>
#include <hip/hip_bf16.h>

#define B_ 32
#define T_ 512
#define TP_ 514          /* padded rows per batch */
#define L_ 2048
#define H_ 512
#define NRR (B_*T_)      /* 16384 rows */
#define KC_ 1536         /* 3*H */
#define NB_ 256
#define EPS_ 1e-5f
#define XPE ((size_t)B_ * TP_ * H_)   /* elems per padded buffer */

typedef __bf16 bf16;
typedef __bf16 bf16x8 __attribute__((ext_vector_type(8)));
typedef float f32x4 __attribute__((ext_vector_type(4)));

static const size_t WC_BYTES  = (size_t)6 * H_ * KC_ * 2;       // 9,437,184
static const size_t XP_BYTES  = XPE * 2;                        // 16,842,752
static const size_t Y_BYTES   = (size_t)3 * NRR * H_ * 2;       // 50,331,648

__device__ __forceinline__ void gload16(const void* g, void* l) {
    __builtin_amdgcn_global_load_lds(
        (const __attribute__((address_space(1))) unsigned int*)g,
        (__attribute__((address_space(3))) unsigned int*)l, 16, 0, 0);
}

// ---------------- weight repack: w[i][o][c][k] -> Wc[m][o][k*H + c] (bf16) ----
__global__ void k_prep_wc(const float* __restrict__ wd, const float* __restrict__ wp,
                          const float* __restrict__ we, bf16* __restrict__ wc) {
    int e = blockIdx.x * 256 + threadIdx.x;
    if (e >= 6 * H_ * KC_) return;
    int m   = e / (H_ * KC_);
    int rem = e % (H_ * KC_);
    int o  = rem / KC_;
    int r2 = rem % KC_;
    int k  = r2 / H_;
    int c  = r2 % H_;
    int p = m >> 1, i = m & 1;
    const float* w = (p == 0) ? wd : (p == 1 ? wp : we);
    float v = w[((size_t)i * H_ * H_ + (size_t)o * H_ + c) * 3 + k];
    wc[e] = (bf16)v;
}

// ---------------- padded bf16 input + zero pad rows of the 3 xp1 buffers -----
__global__ void k_pad(const float* __restrict__ x, bf16* __restrict__ xp0,
                      bf16* __restrict__ xp1) {
    int wid = threadIdx.x >> 6, lane = threadIdx.x & 63;
    int row = blockIdx.x * 4 + wid;               // 0 .. 32*514-1
    int b = row / TP_, tp = row % TP_;
    bf16* d0 = xp0 + (size_t)row * H_ + lane * 8;
    if (tp == 0 || tp == TP_ - 1) {
        bf16x8 z;
#pragma unroll
        for (int i = 0; i < 8; ++i) z[i] = (bf16)0.0f;
        *(bf16x8*)d0 = z;
#pragma unroll
        for (int p = 0; p < 3; ++p)
            *(bf16x8*)(xp1 + p * XPE + (size_t)row * H_ + lane * 8) = z;
    } else {
        const f32x4* p = (const f32x4*)(x + ((size_t)(b * T_ + tp - 1)) * H_ + lane * 8);
        f32x4 u = p[0], v = p[1];
        bf16x8 o;
        o[0] = (bf16)u[0]; o[1] = (bf16)u[1]; o[2] = (bf16)u[2]; o[3] = (bf16)u[3];
        o[4] = (bf16)v[0]; o[5] = (bf16)v[1]; o[6] = (bf16)v[2]; o[7] = (bf16)v[3];
        *(bf16x8*)d0 = o;
    }
}

// ---------------- bucketize (searchsorted left over 255 bins) ----------------
__global__ void k_buckets(const float* __restrict__ pt, const float* __restrict__ et,
                          const float* __restrict__ pbins, const float* __restrict__ ebins,
                          int* __restrict__ pidx, int* __restrict__ eidx) {
    int r = blockIdx.x * 256 + threadIdx.x;
    if (r >= NRR) return;
    {
        float v = pt[r];
        int lo = 0, hi = NB_ - 1;
        while (lo < hi) { int mid = (lo + hi) >> 1; if (pbins[mid] < v) lo = mid + 1; else hi = mid; }
        pidx[r] = lo;
    }
    {
        float v = et[r];
        int lo = 0, hi = NB_ - 1;
        while (lo < hi) { int mid = (lo + hi) >> 1; if (ebins[mid] < v) lo = mid + 1; else hi = mid; }
        eidx[r] = lo;
    }
}

// ---------------- per-batch inclusive scan of durations ----------------------
__global__ void k_scan(const int* __restrict__ dur, int* __restrict__ csum,
                       float* __restrict__ mel_out) {
    int b = blockIdx.x, t = threadIdx.x;
    __shared__ int s[T_];
    s[t] = dur[b * T_ + t];
    __syncthreads();
    for (int off = 1; off < T_; off <<= 1) {
        int v = (t >= off) ? s[t - off] : 0;
        __syncthreads();
        s[t] += v;
        __syncthreads();
    }
    csum[b * T_ + t] = s[t];
    if (t == T_ - 1) mel_out[b] = (float)((s[t] < L_) ? s[t] : L_);
}

// ---------------- length regulate + (x + p_emb + e_emb) gather ---------------
__global__ void k_gather(const float* __restrict__ x, const float* __restrict__ pemb,
                         const float* __restrict__ eemb, const int* __restrict__ pidx,
                         const int* __restrict__ eidx, const int* __restrict__ csum,
                         float* __restrict__ out) {
    int bi = blockIdx.x;
    int b  = bi >> 9;
    int l0 = (bi & 511) << 2;
    __shared__ int cs[T_];
    cs[threadIdx.x]       = csum[b * T_ + threadIdx.x];
    cs[threadIdx.x + 256] = csum[b * T_ + threadIdx.x + 256];
    __syncthreads();
    int wid = threadIdx.x >> 6, lane = threadIdx.x & 63;
    int l = l0 + wid;
    int mel = cs[T_ - 1]; if (mel > L_) mel = L_;
    float* op = out + ((size_t)(b * L_ + l)) * H_ + lane * 8;
    if (l >= mel) {
        f32x4 z = {0.f, 0.f, 0.f, 0.f};
        ((f32x4*)op)[0] = z;
        ((f32x4*)op)[1] = z;
        return;
    }
    int lo = 0, hi = T_;
    while (lo < hi) { int mid = (lo + hi) >> 1; if (cs[mid] <= l) lo = mid + 1; else hi = mid; }
    int idx = (lo < T_ - 1) ? lo : (T_ - 1);
    int rr = b * T_ + idx;
    int pi = pidx[rr], ei = eidx[rr];
    const f32x4* xp = (const f32x4*)(x    + (size_t)rr * H_ + lane * 8);
    const f32x4* pp = (const f32x4*)(pemb + (size_t)pi * H_ + lane * 8);
    const f32x4* ep = (const f32x4*)(eemb + (size_t)ei * H_ + lane * 8);
    ((f32x4*)op)[0] = xp[0] + pp[0] + ep[0];
    ((f32x4*)op)[1] = xp[1] + pp[1] + ep[1];
}

// ---------------- tiled conv-as-GEMM (m97 structure), batched over predictors
// LAYER 0: grid(12,128)   — A shared (xp0), cols 0..1535 span the 3 predictors
// LAYER 1: grid(4,128,3)  — A = xp1[p]
// Y layout: [p][row][512] bf16
template<int LAYER>
__global__ void k_gemm(const bf16* __restrict__ Xp, const bf16* __restrict__ Wall,
                       const float* __restrict__ cb0, const float* __restrict__ cb1,
                       const float* __restrict__ cb2, bf16* __restrict__ Y) {
    __shared__ bf16 lA[128 * 64];
    __shared__ bf16 lB[128 * 64];
    int p, oBase;
    const bf16* A;
    const bf16* W;
    if constexpr (LAYER == 0) {
        int cB = blockIdx.x * 128;
        p = cB >> 9; oBase = cB & 511;
        A = Xp;
        W = Wall + ((size_t)(2 * p) * H_ + oBase) * KC_;
    } else {
        p = blockIdx.z; oBase = blockIdx.x * 128;
        A = Xp + (size_t)p * XPE;
        W = Wall + ((size_t)(2 * p + 1) * H_ + oBase) * KC_;
    }
    const float* cbp  = (p == 0) ? cb0 : (p == 1 ? cb1 : cb2);
    const float* bias = cbp + (LAYER ? H_ : 0);

    int tid = threadIdx.x;
    int wid = tid >> 6, lane = tid & 63;
    int wr = wid >> 1, wc = wid & 1;
    int rowBase = blockIdx.y * 128;
    int b  = rowBase >> 9;
    int t0 = rowBase & (T_ - 1);

    f32x4 acc[4][4];
#pragma unroll
    for (int m = 0; m < 4; ++m)
#pragma unroll
        for (int n = 0; n < 4; ++n) acc[m][n] = (f32x4){0.f, 0.f, 0.f, 0.f};

    int lr = lane & 15, kq = lane >> 4;
    int rsub = lane >> 3, csub = (lane & 7) << 3;

    for (int step = 0; step < 24; ++step) {
        int k  = step >> 3;
        int c0 = (step & 7) << 6;
        const bf16* srcA = A + ((size_t)(b * TP_ + t0 + k)) * H_ + c0;
        const bf16* srcB = W + step * 64;
#pragma unroll
        for (int q = 0; q < 4; ++q) {
            int r0 = (wid * 4 + q) * 8;
            gload16(srcA + (size_t)(r0 + rsub) * H_  + csub, &lA[r0 * 64]);
            gload16(srcB + (size_t)(r0 + rsub) * KC_ + csub, &lB[r0 * 64]);
        }
        __syncthreads();
#pragma unroll
        for (int kk = 0; kk < 64; kk += 32) {
            bf16x8 af[4], bfr[4];
#pragma unroll
            for (int m = 0; m < 4; ++m)
                af[m] = *(const bf16x8*)&lA[(wr * 64 + m * 16 + lr) * 64 + kk + kq * 8];
#pragma unroll
            for (int n = 0; n < 4; ++n)
                bfr[n] = *(const bf16x8*)&lB[(wc * 64 + n * 16 + lr) * 64 + kk + kq * 8];
#pragma unroll
            for (int m = 0; m < 4; ++m)
#pragma unroll
                for (int n = 0; n < 4; ++n)
                    acc[m][n] = __builtin_amdgcn_mfma_f32_16x16x32_bf16(af[m], bfr[n], acc[m][n], 0, 0, 0);
        }
        __syncthreads();
    }

    // D layout: col = lane&15 (o), row = 4*(lane>>4) + reg
#pragma unroll
    for (int n = 0; n < 4; ++n) {
        int o = oBase + wc * 64 + n * 16 + lr;
        float bi = bias[o];
#pragma unroll
        for (int m = 0; m < 4; ++m) {
            int row = rowBase + wr * 64 + m * 16 + 4 * kq;
#pragma unroll
            for (int r = 0; r < 4; ++r)
                Y[((size_t)p * NRR + row + r) * H_ + o] = (bf16)fmaxf(acc[m][n][r] + bi, 0.f);
        }
    }
}

// ---------------- batched LayerNorm (layer-0) -> padded xp1[p] ---------------
__global__ void k_ln_store(const bf16* __restrict__ Yin,
                           const float* __restrict__ g0, const float* __restrict__ g1,
                           const float* __restrict__ g2,
                           const float* __restrict__ bb0, const float* __restrict__ bb1,
                           const float* __restrict__ bb2, bf16* __restrict__ xp1) {
    int wid = threadIdx.x >> 6, lane = threadIdx.x & 63;
    int rg = blockIdx.x * 4 + wid;
    int p = rg >> 14, r = rg & (NRR - 1);
    const float* g   = (p == 0) ? g0 : (p == 1 ? g1 : g2);
    const float* bta = (p == 0) ? bb0 : (p == 1 ? bb1 : bb2);
    bf16x8 a = *(const bf16x8*)(Yin + ((size_t)p * NRR + r) * H_ + lane * 8);
    float f[8];
#pragma unroll
    for (int i = 0; i < 8; ++i) f[i] = (float)a[i];
    float s1 = 0.f, s2 = 0.f;
#pragma unroll
    for (int i = 0; i < 8; ++i) { s1 += f[i]; s2 += f[i] * f[i]; }
    for (int m = 1; m < 64; m <<= 1) { s1 += __shfl_xor(s1, m); s2 += __shfl_xor(s2, m); }
    float mean = s1 * (1.f / H_);
    float var  = s2 * (1.f / H_) - mean * mean;
    float rs   = rsqrtf(var + EPS_);
    const f32x4* gp = (const f32x4*)g;
    const f32x4* bp = (const f32x4*)bta;
    f32x4 ga = gp[lane * 2], gb = gp[lane * 2 + 1];
    f32x4 ba = bp[lane * 2], bbv = bp[lane * 2 + 1];
    bf16x8 o;
    o[0] = (bf16)((f[0] - mean) * rs * ga[0] + ba[0]);
    o[1] = (bf16)((f[1] - mean) * rs * ga[1] + ba[1]);
    o[2] = (bf16)((f[2] - mean) * rs * ga[2] + ba[2]);
    o[3] = (bf16)((f[3] - mean) * rs * ga[3] + ba[3]);
    o[4] = (bf16)((f[4] - mean) * rs * gb[0] + bbv[0]);
    o[5] = (bf16)((f[5] - mean) * rs * gb[1] + bbv[1]);
    o[6] = (bf16)((f[6] - mean) * rs * gb[2] + bbv[2]);
    o[7] = (bf16)((f[7] - mean) * rs * gb[3] + bbv[3]);
    int bb = r >> 9, t = r & (T_ - 1);
    *(bf16x8*)(xp1 + (size_t)p * XPE + ((size_t)(bb * TP_ + t + 1)) * H_ + lane * 8) = o;
}

// ---------------- batched LayerNorm (layer-1) + linear H->1 + mask -----------
__global__ void k_ln_linear(const bf16* __restrict__ Yin,
                            const float* __restrict__ g0, const float* __restrict__ g1,
                            const float* __restrict__ g2,
                            const float* __restrict__ bb0, const float* __restrict__ bb1,
                            const float* __restrict__ bb2,
                            const float* __restrict__ w0p, const float* __restrict__ w1p,
                            const float* __restrict__ w2p,
                            const float* __restrict__ lb0, const float* __restrict__ lb1,
                            const float* __restrict__ lb2,
                            const unsigned char* __restrict__ mask,
                            float* __restrict__ o0, float* __restrict__ o1,
                            float* __restrict__ o2) {
    int wid = threadIdx.x >> 6, lane = threadIdx.x & 63;
    int rg = blockIdx.x * 4 + wid;
    int p = rg >> 14, r = rg & (NRR - 1);
    const float* g   = ((p == 0) ? g0 : (p == 1 ? g1 : g2)) + H_;
    const float* bta = ((p == 0) ? bb0 : (p == 1 ? bb1 : bb2)) + H_;
    const float* lw  = (p == 0) ? w0p : (p == 1 ? w1p : w2p);
    const float* lb  = (p == 0) ? lb0 : (p == 1 ? lb1 : lb2);
    float*       op  = (p == 0) ? o0 : (p == 1 ? o1 : o2);
    bf16x8 a = *(const bf16x8*)(Yin + ((size_t)p * NRR + r) * H_ + lane * 8);
    float f[8];
#pragma unroll
    for (int i = 0; i < 8; ++i) f[i] = (float)a[i];
    float s1 = 0.f, s2 = 0.f;
#pragma unroll
    for (int i = 0; i < 8; ++i) { s1 += f[i]; s2 += f[i] * f[i]; }
    for (int m = 1; m < 64; m <<= 1) { s1 += __shfl_xor(s1, m); s2 += __shfl_xor(s2, m); }
    float mean = s1 * (1.f / H_);
    float var  = s2 * (1.f / H_) - mean * mean;
    float rs   = rsqrtf(var + EPS_);
    const f32x4* gp = (const f32x4*)g;
    const f32x4* bp = (const f32x4*)bta;
    const f32x4* wp = (const f32x4*)lw;
    f32x4 ga = gp[lane * 2], gb = gp[lane * 2 + 1];
    f32x4 ba = bp[lane * 2], bbv = bp[lane * 2 + 1];
    f32x4 wa = wp[lane * 2], wb = wp[lane * 2 + 1];
    float s = ((f[0] - mean) * rs * ga[0] + ba[0]) * wa[0]
            + ((f[1] - mean) * rs * ga[1] + ba[1]) * wa[1]
            + ((f[2] - mean) * rs * ga[2] + ba[2]) * wa[2]
            + ((f[3] - mean) * rs * ga[3] + ba[3]) * wa[3]
            + ((f[4] - mean) * rs * gb[0] + bbv[0]) * wb[0]
            + ((f[5] - mean) * rs * gb[1] + bbv[1]) * wb[1]
            + ((f[6] - mean) * rs * gb[2] + bbv[2]) * wb[2]
            + ((f[7] - mean) * rs * gb[3] + bbv[3]) * wb[3];
    for (int m = 1; m < 64; m <<= 1) s += __shfl_xor(s, m);
    if (lane == 0) op[r] = mask[r] ? 0.f : (s + lb[0]);
}

extern "C" void kernel_launch(void* const* d_in, const int* in_sizes, int n_in,
                              void* d_out, int out_size, void* d_ws, size_t ws_size,
                              hipStream_t stream) {
    const float* x  = (const float*)d_in[0];
    const unsigned char* mask = (const unsigned char*)d_in[1];
    const int*   dur = (const int*)d_in[2];
    const float* pt  = (const float*)d_in[3];
    const float* et  = (const float*)d_in[4];
    const float* cw[3]    = {(const float*)d_in[6],  (const float*)d_in[12], (const float*)d_in[18]};
    const float* cb[3]    = {(const float*)d_in[7],  (const float*)d_in[13], (const float*)d_in[19]};
    const float* lg[3]    = {(const float*)d_in[8],  (const float*)d_in[14], (const float*)d_in[20]};
    const float* lbn[3]   = {(const float*)d_in[9],  (const float*)d_in[15], (const float*)d_in[21]};
    const float* lw[3]    = {(const float*)d_in[10], (const float*)d_in[16], (const float*)d_in[22]};
    const float* lbias[3] = {(const float*)d_in[11], (const float*)d_in[17], (const float*)d_in[23]};
    const float* pbins = (const float*)d_in[24];
    const float* ebins = (const float*)d_in[25];
    const float* pemb  = (const float*)d_in[26];
    const float* eemb  = (const float*)d_in[27];

    float* out0 = (float*)d_out;
    const size_t OUT0 = (size_t)B_ * L_ * H_;
    float* pitch_out  = out0 + OUT0;
    float* energy_out = pitch_out + NRR;
    float* logd_out   = energy_out + NRR;
    float* mel_out    = logd_out + NRR;

    char* ws = (char*)d_ws;
    bf16*  wc   = (bf16*)ws;
    bf16*  xp0  = (bf16*)(ws + WC_BYTES);
    bf16*  xp1  = (bf16*)(ws + WC_BYTES + XP_BYTES);          // 3 buffers
    bf16*  y    = (bf16*)(ws + WC_BYTES + 4 * XP_BYTES);      // [3][NRR][512]
    int*   csum = (int*)(ws + WC_BYTES + 4 * XP_BYTES + Y_BYTES);
    int*   pidx = csum + NRR;
    int*   eidx = pidx + NRR;

    k_prep_wc<<<(6 * H_ * KC_ + 255) / 256, 256, 0, stream>>>(cw[0], cw[1], cw[2], wc);
    k_pad<<<B_ * TP_ / 4, 256, 0, stream>>>(x, xp0, xp1);
    k_buckets<<<(NRR + 255) / 256, 256, 0, stream>>>(pt, et, pbins, ebins, pidx, eidx);
    k_scan<<<B_, T_, 0, stream>>>(dur, csum, mel_out);
    k_gather<<<B_ * L_ / 4, 256, 0, stream>>>(x, pemb, eemb, pidx, eidx, csum, out0);

    dim3 g0(12, 128);
    k_gemm<0><<<g0, 256, 0, stream>>>(xp0, wc, cb[0], cb[1], cb[2], y);
    k_ln_store<<<3 * NRR / 4, 256, 0, stream>>>(y, lg[0], lg[1], lg[2],
                                                lbn[0], lbn[1], lbn[2], xp1);
    dim3 g1(4, 128, 3);
    k_gemm<1><<<g1, 256, 0, stream>>>(xp1, wc, cb[0], cb[1], cb[2], y);
    k_ln_linear<<<3 * NRR / 4, 256, 0, stream>>>(y, lg[0], lg[1], lg[2],
                                                 lbn[0], lbn[1], lbn[2],
                                                 lw[0], lw[1], lw[2],
                                                 lbias[0], lbias[1], lbias[2],
                                                 mask, logd_out, pitch_out, energy_out);
}

// Round 4
// 257.479 us; speedup vs baseline: 5.9321x; 1.1735x over previous
//
#include <hip/hip_runtime.h>
#include <hip/hip_bf16.h>

#define B_ 32
#define T_ 512
#define TP_ 514          /* padded rows per batch */
#define L_ 2048
#define H_ 512
#define NRR (B_*T_)      /* 16384 rows */
#define KC_ 1536         /* 3*H */
#define NB_ 256
#define EPS_ 1e-5f
#define XPE ((size_t)B_ * TP_ * H_)   /* elems per padded buffer */

typedef __bf16 bf16;
typedef __bf16 bf16x8 __attribute__((ext_vector_type(8)));
typedef float f32x4 __attribute__((ext_vector_type(4)));

static const size_t WC_BYTES  = (size_t)6 * H_ * KC_ * 2;       // 9,437,184
static const size_t XP_BYTES  = XPE * 2;                        // 16,842,752
static const size_t Y_BYTES   = (size_t)3 * NRR * H_ * 2;       // 50,331,648

__device__ __forceinline__ void gload16(const void* g, void* l) {
    __builtin_amdgcn_global_load_lds(
        (const __attribute__((address_space(1))) unsigned int*)g,
        (__attribute__((address_space(3))) unsigned int*)l, 16, 0, 0);
}

// ---------------- weight repack: w[i][o][c][k] -> Wc[m][o][k*H + c] (bf16) ----
__global__ void k_prep_wc(const float* __restrict__ wd, const float* __restrict__ wp,
                          const float* __restrict__ we, bf16* __restrict__ wc) {
    int e = blockIdx.x * 256 + threadIdx.x;
    if (e >= 6 * H_ * KC_) return;
    int m   = e / (H_ * KC_);
    int rem = e % (H_ * KC_);
    int o  = rem / KC_;
    int r2 = rem % KC_;
    int k  = r2 / H_;
    int c  = r2 % H_;
    int p = m >> 1, i = m & 1;
    const float* w = (p == 0) ? wd : (p == 1 ? wp : we);
    float v = w[((size_t)i * H_ * H_ + (size_t)o * H_ + c) * 3 + k];
    wc[e] = (bf16)v;
}

// ---------------- padded bf16 input + zero pad rows of the 3 xp1 buffers -----
__global__ void k_pad(const float* __restrict__ x, bf16* __restrict__ xp0,
                      bf16* __restrict__ xp1) {
    int wid = threadIdx.x >> 6, lane = threadIdx.x & 63;
    int row = blockIdx.x * 4 + wid;               // 0 .. 32*514-1
    int b = row / TP_, tp = row % TP_;
    bf16* d0 = xp0 + (size_t)row * H_ + lane * 8;
    if (tp == 0 || tp == TP_ - 1) {
        bf16x8 z;
#pragma unroll
        for (int i = 0; i < 8; ++i) z[i] = (bf16)0.0f;
        *(bf16x8*)d0 = z;
#pragma unroll
        for (int p = 0; p < 3; ++p)
            *(bf16x8*)(xp1 + p * XPE + (size_t)row * H_ + lane * 8) = z;
    } else {
        const f32x4* p = (const f32x4*)(x + ((size_t)(b * T_ + tp - 1)) * H_ + lane * 8);
        f32x4 u = p[0], v = p[1];
        bf16x8 o;
        o[0] = (bf16)u[0]; o[1] = (bf16)u[1]; o[2] = (bf16)u[2]; o[3] = (bf16)u[3];
        o[4] = (bf16)v[0]; o[5] = (bf16)v[1]; o[6] = (bf16)v[2]; o[7] = (bf16)v[3];
        *(bf16x8*)d0 = o;
    }
}

// ---------------- bucketize (searchsorted left over 255 bins) ----------------
__global__ void k_buckets(const float* __restrict__ pt, const float* __restrict__ et,
                          const float* __restrict__ pbins, const float* __restrict__ ebins,
                          int* __restrict__ pidx, int* __restrict__ eidx) {
    int r = blockIdx.x * 256 + threadIdx.x;
    if (r >= NRR) return;
    {
        float v = pt[r];
        int lo = 0, hi = NB_ - 1;
        while (lo < hi) { int mid = (lo + hi) >> 1; if (pbins[mid] < v) lo = mid + 1; else hi = mid; }
        pidx[r] = lo;
    }
    {
        float v = et[r];
        int lo = 0, hi = NB_ - 1;
        while (lo < hi) { int mid = (lo + hi) >> 1; if (ebins[mid] < v) lo = mid + 1; else hi = mid; }
        eidx[r] = lo;
    }
}

// ---------------- per-batch inclusive scan of durations ----------------------
__global__ void k_scan(const int* __restrict__ dur, int* __restrict__ csum,
                       float* __restrict__ mel_out) {
    int b = blockIdx.x, t = threadIdx.x;
    __shared__ int s[T_];
    s[t] = dur[b * T_ + t];
    __syncthreads();
    for (int off = 1; off < T_; off <<= 1) {
        int v = (t >= off) ? s[t - off] : 0;
        __syncthreads();
        s[t] += v;
        __syncthreads();
    }
    csum[b * T_ + t] = s[t];
    if (t == T_ - 1) mel_out[b] = (float)((s[t] < L_) ? s[t] : L_);
}

// ---------------- length regulate + (x + p_emb + e_emb) gather ---------------
__global__ void k_gather(const float* __restrict__ x, const float* __restrict__ pemb,
                         const float* __restrict__ eemb, const int* __restrict__ pidx,
                         const int* __restrict__ eidx, const int* __restrict__ csum,
                         float* __restrict__ out) {
    int bi = blockIdx.x;
    int b  = bi >> 9;
    int l0 = (bi & 511) << 2;
    __shared__ int cs[T_];
    cs[threadIdx.x]       = csum[b * T_ + threadIdx.x];
    cs[threadIdx.x + 256] = csum[b * T_ + threadIdx.x + 256];
    __syncthreads();
    int wid = threadIdx.x >> 6, lane = threadIdx.x & 63;
    int l = l0 + wid;
    int mel = cs[T_ - 1]; if (mel > L_) mel = L_;
    float* op = out + ((size_t)(b * L_ + l)) * H_ + lane * 8;
    if (l >= mel) {
        f32x4 z = {0.f, 0.f, 0.f, 0.f};
        ((f32x4*)op)[0] = z;
        ((f32x4*)op)[1] = z;
        return;
    }
    int lo = 0, hi = T_;
    while (lo < hi) { int mid = (lo + hi) >> 1; if (cs[mid] <= l) lo = mid + 1; else hi = mid; }
    int idx = (lo < T_ - 1) ? lo : (T_ - 1);
    int rr = b * T_ + idx;
    int pi = pidx[rr], ei = eidx[rr];
    const f32x4* xp = (const f32x4*)(x    + (size_t)rr * H_ + lane * 8);
    const f32x4* pp = (const f32x4*)(pemb + (size_t)pi * H_ + lane * 8);
    const f32x4* ep = (const f32x4*)(eemb + (size_t)ei * H_ + lane * 8);
    ((f32x4*)op)[0] = xp[0] + pp[0] + ep[0];
    ((f32x4*)op)[1] = xp[1] + pp[1] + ep[1];
}

// ---------------- tiled conv-as-GEMM (m97 structure + T1 XCD-chunk + T2 swz)
// LAYER 0: 1536 blocks — A shared (xp0), cols 0..1535 span the 3 predictors
// LAYER 1: 1536 blocks — A = xp1[p], cols 0..511, p = predictor
// LDS swizzle: LDS[r][c8] holds G[r][c8 ^ (r&7)] (16B chunks), both A and B.
template<int LAYER>
__global__ void k_gemm(const bf16* __restrict__ Xp, const bf16* __restrict__ Wall,
                       const float* __restrict__ cb0, const float* __restrict__ cb1,
                       const float* __restrict__ cb2, bf16* __restrict__ Y) {
    __shared__ bf16 lA[128 * 64];
    __shared__ bf16 lB[128 * 64];

    // T1: bijective XCD-chunked swizzle; nwg = 1536 = 8 * 192 exactly.
    int bid = blockIdx.x;
    int swz = (bid & 7) * 192 + (bid >> 3);

    int p, oBase, rowBase;
    const bf16* A;
    const bf16* W;
    if constexpr (LAYER == 0) {
        int colblk = swz % 12;           // col-block fastest: 12 share one A-panel
        int rowblk = swz / 12;
        int cB = colblk * 128;
        p = cB >> 9; oBase = cB & 511;
        rowBase = rowblk * 128;
        A = Xp;
        W = Wall + ((size_t)(2 * p) * H_ + oBase) * KC_;
    } else {
        int colblk = swz & 3;            // 4 col-blocks share one A-panel
        int rem = swz >> 2;              // p*128 + rowblk
        p = rem >> 7;
        rowBase = (rem & 127) * 128;
        oBase = colblk * 128;
        A = Xp + (size_t)p * XPE;
        W = Wall + ((size_t)(2 * p + 1) * H_ + oBase) * KC_;
    }
    const float* cbp  = (p == 0) ? cb0 : (p == 1 ? cb1 : cb2);
    const float* bias = cbp + (LAYER ? H_ : 0);

    int tid = threadIdx.x;
    int wid = tid >> 6, lane = tid & 63;
    int wr = wid >> 1, wc = wid & 1;
    int b  = rowBase >> 9;
    int t0 = rowBase & (T_ - 1);

    f32x4 acc[4][4];
#pragma unroll
    for (int m = 0; m < 4; ++m)
#pragma unroll
        for (int n = 0; n < 4; ++n) acc[m][n] = (f32x4){0.f, 0.f, 0.f, 0.f};

    int lr = lane & 15, kq = lane >> 4;
    int xr = lr & 7;                               // ds_read col XOR key
    int rsub = lane >> 3;
    int csw  = ((lane & 7) ^ rsub) << 3;           // T2 pre-swizzled source col

    for (int step = 0; step < 24; ++step) {
        int k  = step >> 3;
        int c0 = (step & 7) << 6;
        const bf16* srcA = A + ((size_t)(b * TP_ + t0 + k)) * H_ + c0;
        const bf16* srcB = W + step * 64;
#pragma unroll
        for (int q = 0; q < 4; ++q) {
            int r0 = (wid * 4 + q) * 8;
            gload16(srcA + (size_t)(r0 + rsub) * H_  + csw, &lA[r0 * 64]);
            gload16(srcB + (size_t)(r0 + rsub) * KC_ + csw, &lB[r0 * 64]);
        }
        __syncthreads();
#pragma unroll
        for (int kk = 0; kk < 64; kk += 32) {
            bf16x8 af[4], bfr[4];
            int c8 = (kk >> 3) + kq;               // logical 16B chunk 0..7
#pragma unroll
            for (int m = 0; m < 4; ++m)
                af[m] = *(const bf16x8*)&lA[(wr * 64 + m * 16 + lr) * 64 + ((c8 ^ xr) << 3)];
#pragma unroll
            for (int n = 0; n < 4; ++n)
                bfr[n] = *(const bf16x8*)&lB[(wc * 64 + n * 16 + lr) * 64 + ((c8 ^ xr) << 3)];
#pragma unroll
            for (int m = 0; m < 4; ++m)
#pragma unroll
                for (int n = 0; n < 4; ++n)
                    acc[m][n] = __builtin_amdgcn_mfma_f32_16x16x32_bf16(af[m], bfr[n], acc[m][n], 0, 0, 0);
        }
        __syncthreads();
    }

    // D layout: col = lane&15 (o), row = 4*(lane>>4) + reg
#pragma unroll
    for (int n = 0; n < 4; ++n) {
        int o = oBase + wc * 64 + n * 16 + lr;
        float bi = bias[o];
#pragma unroll
        for (int m = 0; m < 4; ++m) {
            int row = rowBase + wr * 64 + m * 16 + 4 * kq;
#pragma unroll
            for (int r = 0; r < 4; ++r)
                Y[((size_t)p * NRR + row + r) * H_ + o] = (bf16)fmaxf(acc[m][n][r] + bi, 0.f);
        }
    }
}

// ---------------- batched LayerNorm (layer-0) -> padded xp1[p] ---------------
__global__ void k_ln_store(const bf16* __restrict__ Yin,
                           const float* __restrict__ g0, const float* __restrict__ g1,
                           const float* __restrict__ g2,
                           const float* __restrict__ bb0, const float* __restrict__ bb1,
                           const float* __restrict__ bb2, bf16* __restrict__ xp1) {
    int wid = threadIdx.x >> 6, lane = threadIdx.x & 63;
    int rg = blockIdx.x * 4 + wid;
    int p = rg >> 14, r = rg & (NRR - 1);
    const float* g   = (p == 0) ? g0 : (p == 1 ? g1 : g2);
    const float* bta = (p == 0) ? bb0 : (p == 1 ? bb1 : bb2);
    bf16x8 a = *(const bf16x8*)(Yin + ((size_t)p * NRR + r) * H_ + lane * 8);
    float f[8];
#pragma unroll
    for (int i = 0; i < 8; ++i) f[i] = (float)a[i];
    float s1 = 0.f, s2 = 0.f;
#pragma unroll
    for (int i = 0; i < 8; ++i) { s1 += f[i]; s2 += f[i] * f[i]; }
    for (int m = 1; m < 64; m <<= 1) { s1 += __shfl_xor(s1, m); s2 += __shfl_xor(s2, m); }
    float mean = s1 * (1.f / H_);
    float var  = s2 * (1.f / H_) - mean * mean;
    float rs   = rsqrtf(var + EPS_);
    const f32x4* gp = (const f32x4*)g;
    const f32x4* bp = (const f32x4*)bta;
    f32x4 ga = gp[lane * 2], gb = gp[lane * 2 + 1];
    f32x4 ba = bp[lane * 2], bbv = bp[lane * 2 + 1];
    bf16x8 o;
    o[0] = (bf16)((f[0] - mean) * rs * ga[0] + ba[0]);
    o[1] = (bf16)((f[1] - mean) * rs * ga[1] + ba[1]);
    o[2] = (bf16)((f[2] - mean) * rs * ga[2] + ba[2]);
    o[3] = (bf16)((f[3] - mean) * rs * ga[3] + ba[3]);
    o[4] = (bf16)((f[4] - mean) * rs * gb[0] + bbv[0]);
    o[5] = (bf16)((f[5] - mean) * rs * gb[1] + bbv[1]);
    o[6] = (bf16)((f[6] - mean) * rs * gb[2] + bbv[2]);
    o[7] = (bf16)((f[7] - mean) * rs * gb[3] + bbv[3]);
    int bb = r >> 9, t = r & (T_ - 1);
    *(bf16x8*)(xp1 + (size_t)p * XPE + ((size_t)(bb * TP_ + t + 1)) * H_ + lane * 8) = o;
}

// ---------------- batched LayerNorm (layer-1) + linear H->1 + mask -----------
__global__ void k_ln_linear(const bf16* __restrict__ Yin,
                            const float* __restrict__ g0, const float* __restrict__ g1,
                            const float* __restrict__ g2,
                            const float* __restrict__ bb0, const float* __restrict__ bb1,
                            const float* __restrict__ bb2,
                            const float* __restrict__ w0p, const float* __restrict__ w1p,
                            const float* __restrict__ w2p,
                            const float* __restrict__ lb0, const float* __restrict__ lb1,
                            const float* __restrict__ lb2,
                            const unsigned char* __restrict__ mask,
                            float* __restrict__ o0, float* __restrict__ o1,
                            float* __restrict__ o2) {
    int wid = threadIdx.x >> 6, lane = threadIdx.x & 63;
    int rg = blockIdx.x * 4 + wid;
    int p = rg >> 14, r = rg & (NRR - 1);
    const float* g   = ((p == 0) ? g0 : (p == 1 ? g1 : g2)) + H_;
    const float* bta = ((p == 0) ? bb0 : (p == 1 ? bb1 : bb2)) + H_;
    const float* lw  = (p == 0) ? w0p : (p == 1 ? w1p : w2p);
    const float* lb  = (p == 0) ? lb0 : (p == 1 ? lb1 : lb2);
    float*       op  = (p == 0) ? o0 : (p == 1 ? o1 : o2);
    bf16x8 a = *(const bf16x8*)(Yin + ((size_t)p * NRR + r) * H_ + lane * 8);
    float f[8];
#pragma unroll
    for (int i = 0; i < 8; ++i) f[i] = (float)a[i];
    float s1 = 0.f, s2 = 0.f;
#pragma unroll
    for (int i = 0; i < 8; ++i) { s1 += f[i]; s2 += f[i] * f[i]; }
    for (int m = 1; m < 64; m <<= 1) { s1 += __shfl_xor(s1, m); s2 += __shfl_xor(s2, m); }
    float mean = s1 * (1.f / H_);
    float var  = s2 * (1.f / H_) - mean * mean;
    float rs   = rsqrtf(var + EPS_);
    const f32x4* gp = (const f32x4*)g;
    const f32x4* bp = (const f32x4*)bta;
    const f32x4* wp = (const f32x4*)lw;
    f32x4 ga = gp[lane * 2], gb = gp[lane * 2 + 1];
    f32x4 ba = bp[lane * 2], bbv = bp[lane * 2 + 1];
    f32x4 wa = wp[lane * 2], wb = wp[lane * 2 + 1];
    float s = ((f[0] - mean) * rs * ga[0] + ba[0]) * wa[0]
            + ((f[1] - mean) * rs * ga[1] + ba[1]) * wa[1]
            + ((f[2] - mean) * rs * ga[2] + ba[2]) * wa[2]
            + ((f[3] - mean) * rs * ga[3] + ba[3]) * wa[3]
            + ((f[4] - mean) * rs * gb[0] + bbv[0]) * wb[0]
            + ((f[5] - mean) * rs * gb[1] + bbv[1]) * wb[1]
            + ((f[6] - mean) * rs * gb[2] + bbv[2]) * wb[2]
            + ((f[7] - mean) * rs * gb[3] + bbv[3]) * wb[3];
    for (int m = 1; m < 64; m <<= 1) s += __shfl_xor(s, m);
    if (lane == 0) op[r] = mask[r] ? 0.f : (s + lb[0]);
}

extern "C" void kernel_launch(void* const* d_in, const int* in_sizes, int n_in,
                              void* d_out, int out_size, void* d_ws, size_t ws_size,
                              hipStream_t stream) {
    const float* x  = (const float*)d_in[0];
    const unsigned char* mask = (const unsigned char*)d_in[1];
    const int*   dur = (const int*)d_in[2];
    const float* pt  = (const float*)d_in[3];
    const float* et  = (const float*)d_in[4];
    const float* cw[3]    = {(const float*)d_in[6],  (const float*)d_in[12], (const float*)d_in[18]};
    const float* cb[3]    = {(const float*)d_in[7],  (const float*)d_in[13], (const float*)d_in[19]};
    const float* lg[3]    = {(const float*)d_in[8],  (const float*)d_in[14], (const float*)d_in[20]};
    const float* lbn[3]   = {(const float*)d_in[9],  (const float*)d_in[15], (const float*)d_in[21]};
    const float* lw[3]    = {(const float*)d_in[10], (const float*)d_in[16], (const float*)d_in[22]};
    const float* lbias[3] = {(const float*)d_in[11], (const float*)d_in[17], (const float*)d_in[23]};
    const float* pbins = (const float*)d_in[24];
    const float* ebins = (const float*)d_in[25];
    const float* pemb  = (const float*)d_in[26];
    const float* eemb  = (const float*)d_in[27];

    float* out0 = (float*)d_out;
    const size_t OUT0 = (size_t)B_ * L_ * H_;
    float* pitch_out  = out0 + OUT0;
    float* energy_out = pitch_out + NRR;
    float* logd_out   = energy_out + NRR;
    float* mel_out    = logd_out + NRR;

    char* ws = (char*)d_ws;
    bf16*  wc   = (bf16*)ws;
    bf16*  xp0  = (bf16*)(ws + WC_BYTES);
    bf16*  xp1  = (bf16*)(ws + WC_BYTES + XP_BYTES);          // 3 buffers
    bf16*  y    = (bf16*)(ws + WC_BYTES + 4 * XP_BYTES);      // [3][NRR][512]
    int*   csum = (int*)(ws + WC_BYTES + 4 * XP_BYTES + Y_BYTES);
    int*   pidx = csum + NRR;
    int*   eidx = pidx + NRR;

    k_prep_wc<<<(6 * H_ * KC_ + 255) / 256, 256, 0, stream>>>(cw[0], cw[1], cw[2], wc);
    k_pad<<<B_ * TP_ / 4, 256, 0, stream>>>(x, xp0, xp1);
    k_buckets<<<(NRR + 255) / 256, 256, 0, stream>>>(pt, et, pbins, ebins, pidx, eidx);
    k_scan<<<B_, T_, 0, stream>>>(dur, csum, mel_out);
    k_gather<<<B_ * L_ / 4, 256, 0, stream>>>(x, pemb, eemb, pidx, eidx, csum, out0);

    k_gemm<0><<<1536, 256, 0, stream>>>(xp0, wc, cb[0], cb[1], cb[2], y);
    k_ln_store<<<3 * NRR / 4, 256, 0, stream>>>(y, lg[0], lg[1], lg[2],
                                                lbn[0], lbn[1], lbn[2], xp1);
    k_gemm<1><<<1536, 256, 0, stream>>>(xp1, wc, cb[0], cb[1], cb[2], y);
    k_ln_linear<<<3 * NRR / 4, 256, 0, stream>>>(y, lg[0], lg[1], lg[2],
                                                 lbn[0], lbn[1], lbn[2],
                                                 lw[0], lw[1], lw[2],
                                                 lbias[0], lbias[1], lbias[2],
                                                 mask, logd_out, pitch_out, energy_out);
}